// Round 12
// baseline (201.957 us; speedup 1.0000x reference)
//
#include <hip/hip_runtime.h>
#include <hip/hip_fp16.h>
#include <math.h>

#define NN    50000
#define NE0   800000
#define NE    850000
#define INDIM 128
#define HID   64
#define OUTD  40

#define NB    391          // ceil(50000/128) buckets of 128 dsts
#define BSH   7            // bucket shift (dst >> 7)
#define BCAP  3072         // per-bucket capacity (max load ~2400)

// ---------------------------------------------------------------- bin edges by bucket (bcur pre-inited by k_gemm1)
__global__ __launch_bounds__(512) void k_bin(const int* __restrict__ ei,
                                             int* __restrict__ bcur,
                                             unsigned int* __restrict__ epack) {
    __shared__ int lh[NB];
    __shared__ int lbase[NB];
    __shared__ unsigned ebuf[3328];
    const int tid = threadIdx.x;
    const int CH = (NE + 255) / 256;           // 3321
    const int e0 = blockIdx.x * CH;
    const int e1 = (e0 + CH < NE) ? e0 + CH : NE;
    const int cnt = e1 - e0;

    for (int i = tid; i < NB; i += 512) lh[i] = 0;
    __syncthreads();
    for (int i = tid; i < cnt; i += 512) {
        int e = e0 + i;
        int src, dst;
        if (e < NE0) { src = ei[e]; dst = ei[NE0 + e]; }
        else         { src = e - NE0; dst = src; }
        int bkt = dst >> BSH;
        ebuf[i] = (unsigned)src | ((unsigned)(dst & 127) << 16) | ((unsigned)bkt << 23);
        atomicAdd(&lh[bkt], 1);
    }
    __syncthreads();
    for (int i = tid; i < NB; i += 512) {
        int c = lh[i];
        lbase[i] = c ? atomicAdd(&bcur[i], c) : 0;
        lh[i] = 0;
    }
    __syncthreads();
    for (int i = tid; i < cnt; i += 512) {
        unsigned rec = ebuf[i];
        int bkt = rec >> 23;
        int lpos = atomicAdd(&lh[bkt], 1);
        epack[lbase[bkt] + lpos] = rec & 0x7FFFFFu;
    }
}

// ---------------------------------------------------------------- per-bucket fine CSR (pure: off + esrc only)
__global__ __launch_bounds__(512) void k_bucket_csr(
    const int* __restrict__ bcur, const unsigned int* __restrict__ epack,
    int* __restrict__ off_s, int* __restrict__ off_e, int* __restrict__ esrc) {
    __shared__ int lh[128];
    __shared__ int lcur[128];
    __shared__ int sblk;
    const int tid = threadIdx.x, lane = tid & 63;
    const int b = blockIdx.x;
    const int e0 = b * BCAP;
    const int cnt = bcur[b] - e0;

    if (tid < 128) lh[tid] = 0;
    __syncthreads();
    for (int i = tid; i < cnt; i += 512)
        atomicAdd(&lh[epack[e0 + i] >> 16], 1);
    __syncthreads();

    int v = 0, incl = 0;
    if (tid < 128) {
        v = lh[tid];
        incl = v;
#pragma unroll
        for (int s = 1; s < 64; s <<= 1) {
            int t = __shfl_up(incl, s);
            if (lane >= s) incl += t;
        }
    }
    if (tid == 63) sblk = incl;
    __syncthreads();
    if (tid >= 64 && tid < 128) incl += sblk;
    if (tid < 128) {
        int ex = e0 + incl - v;
        lcur[tid] = ex;
        int gd = b * 128 + tid;
        if (gd < NN) { off_s[gd] = ex; off_e[gd] = ex + v; }
    }
    __syncthreads();

    for (int i = tid; i < cnt; i += 512) {
        unsigned int p = epack[e0 + i];
        int pos = atomicAdd(&lcur[p >> 16], 1);
        esrc[pos] = (int)(p & 0xFFFFu);
    }
}

// ---------------------------------------------------------------- GEMM1: x(50000x128)@W1(128x64), 4x4 reg tile, fp16 h1 out
// also inits bcur (runs first in stream order)
__global__ __launch_bounds__(256, 2) void k_gemm1(
    const float* __restrict__ x, const float* __restrict__ W1,
    const float* __restrict__ a_s, const float* __restrict__ a_d,
    __half* __restrict__ h1h, float* __restrict__ asrc1, float* __restrict__ adst1,
    int* __restrict__ bcur)
{
    __shared__ float Wl[INDIM * HID];      // 32 KB
    __shared__ float xs[64 * 132];         // 33.8 KB, padded stride 132
    const int tid = threadIdx.x;
    const int r0 = blockIdx.x * 64;

    if (blockIdx.x == 0) {
        for (int i = tid; i < NB; i += 256) bcur[i] = i * BCAP;
    }

    const float4* W4 = (const float4*)W1;
    float4* Wl4 = (float4*)Wl;
#pragma unroll
    for (int i = 0; i < 8; ++i) Wl4[tid + i * 256] = W4[tid + i * 256];

    const float4* x4 = (const float4*)x;
#pragma unroll
    for (int i = 0; i < 8; ++i) {
        int idx = tid + i * 256;           // 0..2047
        int row = idx >> 5;                // 32 float4 per row
        int k4  = idx & 31;
        int nr = r0 + row;
        float4 v = make_float4(0.f, 0.f, 0.f, 0.f);
        if (nr < NN) v = x4[(size_t)nr * 32 + k4];
        *(float4*)&xs[row * 132 + k4 * 4] = v;
    }
    __syncthreads();

    const int rg = tid >> 4;               // 0..15 (4 rows each)
    const int cg = tid & 15;
    const int c4 = cg * 4;
    const float as0 = a_s[c4], as1v = a_s[c4+1], as2v = a_s[c4+2], as3v = a_s[c4+3];
    const float ad0 = a_d[c4], ad1v = a_d[c4+1], ad2v = a_d[c4+2], ad3v = a_d[c4+3];

    float acc[4][4];
#pragma unroll
    for (int i = 0; i < 4; ++i)
#pragma unroll
        for (int j = 0; j < 4; ++j) acc[i][j] = 0.f;

#pragma unroll 4
    for (int k4 = 0; k4 < 32; ++k4) {
        float4 xv[4];
#pragma unroll
        for (int i = 0; i < 4; ++i)
            xv[i] = *(const float4*)&xs[(rg * 4 + i) * 132 + k4 * 4];
        const float* wp = &Wl[(k4 * 4) * HID + c4];
        float4 w0 = *(const float4*)(wp);
        float4 w1 = *(const float4*)(wp + HID);
        float4 w2 = *(const float4*)(wp + 2 * HID);
        float4 w3 = *(const float4*)(wp + 3 * HID);
#pragma unroll
        for (int i = 0; i < 4; ++i) {
            acc[i][0] += xv[i].x * w0.x + xv[i].y * w1.x + xv[i].z * w2.x + xv[i].w * w3.x;
            acc[i][1] += xv[i].x * w0.y + xv[i].y * w1.y + xv[i].z * w2.y + xv[i].w * w3.y;
            acc[i][2] += xv[i].x * w0.z + xv[i].y * w1.z + xv[i].z * w2.z + xv[i].w * w3.z;
            acc[i][3] += xv[i].x * w0.w + xv[i].y * w1.w + xv[i].z * w2.w + xv[i].w * w3.w;
        }
    }

#pragma unroll
    for (int i = 0; i < 4; ++i) {
        const int n = r0 + rg * 4 + i;
        if (n < NN) {
            __half2 ha = __floats2half2_rn(acc[i][0], acc[i][1]);
            __half2 hb = __floats2half2_rn(acc[i][2], acc[i][3]);
            *(__half2*)&h1h[(size_t)n * HID + c4]     = ha;
            *(__half2*)&h1h[(size_t)n * HID + c4 + 2] = hb;
        }
        float ps = acc[i][0] * as0 + acc[i][1] * as1v + acc[i][2] * as2v + acc[i][3] * as3v;
        float pd = acc[i][0] * ad0 + acc[i][1] * ad1v + acc[i][2] * ad2v + acc[i][3] * ad3v;
        ps += __shfl_xor(ps, 1); ps += __shfl_xor(ps, 2);
        pd += __shfl_xor(pd, 1); pd += __shfl_xor(pd, 2);
        if ((cg & 3) == 0 && n < NN) {
            int head = cg >> 2;
            asrc1[n * 4 + head] = ps;
            adst1[n * 4 + head] = pd;
        }
    }
}

// ---------------------------------------------------------------- layer-1 aggregate: 8 nodes/wave, 8 lanes x 8 dims (uint4)
__global__ __launch_bounds__(256) void k_fagg1(
    const int* __restrict__ off_s, const int* __restrict__ off_e,
    const int* __restrict__ esrc, const float* __restrict__ asrc1,
    const float* __restrict__ adst1,
    const __half* __restrict__ h1h, const float* __restrict__ b1,
    __half* __restrict__ hmid)
{
    const int wv = threadIdx.x >> 6, lane = threadIdx.x & 63;
    const int g = lane >> 3, li = lane & 7;       // 8 nodes/wave, 8 lanes each
    const int n = blockIdx.x * 32 + wv * 8 + g;   // 1563*32 = 50016
    const bool valid = n < NN;
    const int nc = valid ? n : 0;
    const int s0 = valid ? off_s[nc] : 0;
    const int s1 = valid ? off_e[nc] : 0;
    const int hp = li >> 1;                       // head = (li*8)>>4
    const float adst = adst1[nc * 4 + hp];
    const int last = s1 - 1;

    float l = 0.f;
    float a[8];
#pragma unroll
    for (int k = 0; k < 8; ++k) a[k] = 0.f;
    const char* hb = (const char*)h1h;
    for (int t = s0; t < s1; t += 8) {
        int sx[8];
        int ok[8];
#pragma unroll
        for (int j = 0; j < 8; ++j) {
            int ix  = t + j;
            ok[j] = (ix < s1);
            int ixc = ok[j] ? ix : last;
            sx[j] = esrc[ixc];
        }
        float ax[8];
#pragma unroll
        for (int j = 0; j < 8; ++j) ax[j] = asrc1[sx[j] * 4 + hp];
        uint4 raw[8];
#pragma unroll
        for (int j = 0; j < 8; ++j)
            raw[j] = *(const uint4*)(hb + ((size_t)sx[j] * 128 + li * 16));
#pragma unroll
        for (int j = 0; j < 8; ++j) {
            float e = ax[j] + adst;
            e = (e > 0.f) ? e : 0.2f * e;
            float w = __expf(e);
            w = ok[j] ? w : 0.f;
            l += w;
            float2 p0 = __half22float2(*(__half2*)&raw[j].x);
            float2 p1 = __half22float2(*(__half2*)&raw[j].y);
            float2 p2 = __half22float2(*(__half2*)&raw[j].z);
            float2 p3 = __half22float2(*(__half2*)&raw[j].w);
            a[0] += w * p0.x; a[1] += w * p0.y;
            a[2] += w * p1.x; a[3] += w * p1.y;
            a[4] += w * p2.x; a[5] += w * p2.y;
            a[6] += w * p3.x; a[7] += w * p3.y;
        }
    }
    if (valid) {
        float rcp = 1.f / l;
        float4 bv0 = *(const float4*)&b1[li * 8];
        float4 bv1 = *(const float4*)&b1[li * 8 + 4];
        float o0 = fmaxf(a[0] * rcp + bv0.x, 0.f);
        float o1 = fmaxf(a[1] * rcp + bv0.y, 0.f);
        float o2 = fmaxf(a[2] * rcp + bv0.z, 0.f);
        float o3 = fmaxf(a[3] * rcp + bv0.w, 0.f);
        float o4 = fmaxf(a[4] * rcp + bv1.x, 0.f);
        float o5 = fmaxf(a[5] * rcp + bv1.y, 0.f);
        float o6 = fmaxf(a[6] * rcp + bv1.z, 0.f);
        float o7 = fmaxf(a[7] * rcp + bv1.w, 0.f);
        __half2 q0 = __floats2half2_rn(o0, o1);
        __half2 q1 = __floats2half2_rn(o2, o3);
        __half2 q2 = __floats2half2_rn(o4, o5);
        __half2 q3 = __floats2half2_rn(o6, o7);
        uint4 st;
        st.x = *(unsigned*)&q0; st.y = *(unsigned*)&q1;
        st.z = *(unsigned*)&q2; st.w = *(unsigned*)&q3;
        *(uint4*)((char*)hmid + ((size_t)n * 128 + li * 16)) = st;
    }
}

// ---------------------------------------------------------------- GEMM2: hmid_fp16(50000x64) @ W2(64x40), fp16 h2 out
__global__ __launch_bounds__(320) void k_gemm2(
    const __half* __restrict__ hin, const float* __restrict__ W2,
    const float* __restrict__ a_s, const float* __restrict__ a_d,
    __half* __restrict__ h2h, float* __restrict__ asrc2, float* __restrict__ adst2)
{
    __shared__ float Wl[HID * OUTD];       // 2560 floats
    __shared__ float xs[32 * 68];          // padded stride 68
    __shared__ float s_as[32], s_ad[32];
    const int tid = threadIdx.x;
    const int r0 = blockIdx.x * 32;

    const float4* W4 = (const float4*)W2;  // 640 float4
    float4* Wl4 = (float4*)Wl;
    for (int i = tid; i < 640; i += 320) Wl4[i] = W4[i];
    const uint2* x4 = (const uint2*)hin;   // 4 halfs per uint2; 16 per row
    for (int i = tid; i < 512; i += 320) {
        int row = i >> 4;
        int c   = i & 15;
        int nr = r0 + row;
        float4 v = make_float4(0.f, 0.f, 0.f, 0.f);
        if (nr < NN) {
            uint2 raw = x4[(size_t)nr * 16 + c];
            float2 p0 = __half22float2(*(__half2*)&raw.x);
            float2 p1 = __half22float2(*(__half2*)&raw.y);
            v = make_float4(p0.x, p0.y, p1.x, p1.y);
        }
        *(float4*)&xs[row * 68 + c * 4] = v;
    }
    if (tid < 32) { s_as[tid] = 0.f; s_ad[tid] = 0.f; }
    __syncthreads();

    const int r  = tid / 10;               // 0..31
    const int cg = tid % 10;
    const int c4 = cg * 4;                 // 0..36
    float a0 = 0.f, a1 = 0.f, a2 = 0.f, a3 = 0.f;
#pragma unroll 4
    for (int k4 = 0; k4 < 16; ++k4) {
        float4 xv = *(const float4*)&xs[r * 68 + k4 * 4];
        const float* wp = &Wl[(k4 * 4) * OUTD + c4];
        float4 w0 = *(const float4*)(wp);
        float4 w1 = *(const float4*)(wp + OUTD);
        float4 w2 = *(const float4*)(wp + 2 * OUTD);
        float4 w3 = *(const float4*)(wp + 3 * OUTD);
        a0 += xv.x * w0.x + xv.y * w1.x + xv.z * w2.x + xv.w * w3.x;
        a1 += xv.x * w0.y + xv.y * w1.y + xv.z * w2.y + xv.w * w3.y;
        a2 += xv.x * w0.z + xv.y * w1.z + xv.z * w2.z + xv.w * w3.z;
        a3 += xv.x * w0.w + xv.y * w1.w + xv.z * w2.w + xv.w * w3.w;
    }
    const int n = r0 + r;
    float ps = a0 * a_s[c4] + a1 * a_s[c4 + 1] + a2 * a_s[c4 + 2] + a3 * a_s[c4 + 3];
    float pd = a0 * a_d[c4] + a1 * a_d[c4 + 1] + a2 * a_d[c4 + 2] + a3 * a_d[c4 + 3];
    atomicAdd(&s_as[r], ps);
    atomicAdd(&s_ad[r], pd);
    if (n < NN) {
        __half2 ha = __floats2half2_rn(a0, a1);
        __half2 hb = __floats2half2_rn(a2, a3);
        *(__half2*)&h2h[(size_t)n * OUTD + c4]     = ha;
        *(__half2*)&h2h[(size_t)n * OUTD + c4 + 2] = hb;
    }
    __syncthreads();
    if (tid < 32) {
        int n2 = r0 + tid;
        if (n2 < NN) { asrc2[n2] = s_as[tid]; adst2[n2] = s_ad[tid]; }
    }
}

// ---------------------------------------------------------------- layer-2 aggregate: 12 nodes/wave, 5 lanes x 8 dims, LDS log_softmax
__global__ __launch_bounds__(256) void k_fagg2(
    const int* __restrict__ off_s, const int* __restrict__ off_e,
    const int* __restrict__ esrc, const float* __restrict__ asrc2,
    const float* __restrict__ adst2,
    const __half* __restrict__ h2h, const float* __restrict__ b2,
    float* __restrict__ out)
{
    __shared__ float svals[48][OUTD];
    const int wv = threadIdx.x >> 6, lane = threadIdx.x & 63;
    const int g = lane / 5;                        // 0..12 (g==12 idle)
    const int li = lane - g * 5;                   // 0..4
    const bool ga = (g < 12);
    const int n = blockIdx.x * 48 + wv * 12 + (ga ? g : 0);
    const bool valid = ga && (n < NN);
    const int s0 = valid ? off_s[n] : 0;
    const int s1 = valid ? off_e[n] : 0;
    const float adst = valid ? adst2[n] : 0.f;
    const int last = s1 - 1;

    float l = 0.f;
    float a[8];
#pragma unroll
    for (int k = 0; k < 8; ++k) a[k] = 0.f;
    const char* hb = (const char*)h2h;
    for (int t = s0; t < s1; t += 8) {
        int sx[8];
        int ok[8];
#pragma unroll
        for (int j = 0; j < 8; ++j) {
            int ix  = t + j;
            ok[j] = (ix < s1);
            int ixc = ok[j] ? ix : last;
            sx[j] = esrc[ixc];
        }
        float ax[8];
#pragma unroll
        for (int j = 0; j < 8; ++j) ax[j] = asrc2[sx[j]];
        uint4 raw[8];
#pragma unroll
        for (int j = 0; j < 8; ++j)
            raw[j] = *(const uint4*)(hb + ((size_t)sx[j] * 80 + li * 16));
#pragma unroll
        for (int j = 0; j < 8; ++j) {
            float e = ax[j] + adst;
            e = (e > 0.f) ? e : 0.2f * e;
            float w = __expf(e);
            w = ok[j] ? w : 0.f;
            l += w;
            float2 p0 = __half22float2(*(__half2*)&raw[j].x);
            float2 p1 = __half22float2(*(__half2*)&raw[j].y);
            float2 p2 = __half22float2(*(__half2*)&raw[j].z);
            float2 p3 = __half22float2(*(__half2*)&raw[j].w);
            a[0] += w * p0.x; a[1] += w * p0.y;
            a[2] += w * p1.x; a[3] += w * p1.y;
            a[4] += w * p2.x; a[5] += w * p2.y;
            a[6] += w * p3.x; a[7] += w * p3.y;
        }
    }
    if (valid) {
        float rcp = 1.f / l;
        int r = wv * 12 + g;
#pragma unroll
        for (int k = 0; k < 8; ++k)
            svals[r][li * 8 + k] = a[k] * rcp + b2[li * 8 + k];
    }
    __syncthreads();

    for (int r = wv; r < 48; r += 4) {
        int n2 = blockIdx.x * 48 + r;
        if (n2 >= NN) continue;
        float v = (lane < OUTD) ? svals[r][lane] : -1e30f;
        float mx = v;
#pragma unroll
        for (int o = 32; o; o >>= 1) mx = fmaxf(mx, __shfl_xor(mx, o));
        float ex = (lane < OUTD) ? __expf(v - mx) : 0.f;
        float sm = ex;
#pragma unroll
        for (int o = 32; o; o >>= 1) sm += __shfl_xor(sm, o);
        if (lane < OUTD) out[(size_t)n2 * OUTD + lane] = v - mx - __logf(sm);
    }
}

// ----------------------------------------------------------------
extern "C" void kernel_launch(void* const* d_in, const int* in_sizes, int n_in,
                              void* d_out, int out_size, void* d_ws, size_t ws_size,
                              hipStream_t stream)
{
    const float* x   = (const float*)d_in[0];
    const int*   ei  = (const int*)  d_in[1];
    const float* W1  = (const float*)d_in[2];
    const float* as1 = (const float*)d_in[3];
    const float* ad1 = (const float*)d_in[4];
    const float* b1  = (const float*)d_in[5];
    const float* W2  = (const float*)d_in[6];
    const float* as2 = (const float*)d_in[7];
    const float* ad2 = (const float*)d_in[8];
    const float* b2  = (const float*)d_in[9];
    float* out = (float*)d_out;

    // flat workspace layout (~30 MB of the 268 MB available)
    char* ws = (char*)d_ws;
    __half* h1h   = (__half*)(ws);                        //  6,400,000 B
    __half* hmidh = (__half*)(ws +  6400000);             //  6,400,000 B
    __half* h2h   = (__half*)(ws + 12800000);             //  4,000,000 B
    float*  asrc1 = (float*) (ws + 16800000);             //    800,000 B
    float*  adst1 = (float*) (ws + 17600000);             //    800,000 B
    float*  asrc2 = (float*) (ws + 18400000);             //    200,000 B
    float*  adst2 = (float*) (ws + 18600000);             //    200,000 B
    int*    off_s = (int*)   (ws + 18800000);             //    200,000 B
    int*    off_e = (int*)   (ws + 19000000);             //    200,000 B
    unsigned int* epack = (unsigned int*)(ws + 19200000); //  4,804,608 B (NB*BCAP*4)
    int*    esrc  = (int*)   (ws + 24004608);             //  4,804,608 B
    int*    bcur  = (int*)   (ws + 28809216);             //      1,564 B

    hipLaunchKernelGGL(k_gemm1,      dim3(782),  dim3(256), 0, stream, x, W1, as1, ad1, h1h, asrc1, adst1, bcur);
    hipLaunchKernelGGL(k_bin,        dim3(256),  dim3(512), 0, stream, ei, bcur, epack);
    hipLaunchKernelGGL(k_bucket_csr, dim3(NB),   dim3(512), 0, stream, bcur, epack, off_s, off_e, esrc);
    hipLaunchKernelGGL(k_fagg1,      dim3(1563), dim3(256), 0, stream, off_s, off_e, esrc, asrc1, adst1, h1h, b1, hmidh);
    hipLaunchKernelGGL(k_gemm2,      dim3(1563), dim3(320), 0, stream, hmidh, W2, as2, ad2, h2h, asrc2, adst2);
    hipLaunchKernelGGL(k_fagg2,      dim3(1042), dim3(256), 0, stream, off_s, off_e, esrc, asrc2, adst2, h2h, b2, out);
}

// Round 13
// 191.808 us; speedup vs baseline: 1.0529x; 1.0529x over previous
//
#include <hip/hip_runtime.h>
#include <hip/hip_fp16.h>
#include <math.h>

#define NN    50000
#define NE0   800000
#define NE    850000
#define INDIM 128
#define HID   64
#define OUTD  40

#define NB    391          // ceil(50000/128) buckets of 128 dsts
#define BSH   7            // bucket shift (dst >> 7)
#define BCAP  3072         // per-bucket capacity (max load ~2400)

typedef unsigned short u16;

// ---------------------------------------------------------------- bin edges by bucket (bcur pre-inited by k_gemm1)
__global__ __launch_bounds__(256) void k_bin(const int* __restrict__ ei,
                                             int* __restrict__ bcur,
                                             unsigned int* __restrict__ epack) {
    __shared__ int lh[NB];
    __shared__ int lbase[NB];
    __shared__ unsigned ebuf[3328];
    const int tid = threadIdx.x;
    const int CH = (NE + 255) / 256;           // 3321
    const int e0 = blockIdx.x * CH;
    const int e1 = (e0 + CH < NE) ? e0 + CH : NE;
    const int cnt = e1 - e0;

    for (int i = tid; i < NB; i += 256) lh[i] = 0;
    __syncthreads();
    for (int i = tid; i < cnt; i += 256) {
        int e = e0 + i;
        int src, dst;
        if (e < NE0) { src = ei[e]; dst = ei[NE0 + e]; }
        else         { src = e - NE0; dst = src; }
        int bkt = dst >> BSH;
        ebuf[i] = (unsigned)src | ((unsigned)(dst & 127) << 16) | ((unsigned)bkt << 23);
        atomicAdd(&lh[bkt], 1);
    }
    __syncthreads();
    for (int i = tid; i < NB; i += 256) {
        int c = lh[i];
        lbase[i] = c ? atomicAdd(&bcur[i], c) : 0;
        lh[i] = 0;
    }
    __syncthreads();
    for (int i = tid; i < cnt; i += 256) {
        unsigned rec = ebuf[i];
        int bkt = rec >> 23;
        int lpos = atomicAdd(&lh[bkt], 1);
        epack[lbase[bkt] + lpos] = rec & 0x7FFFFFu;
    }
}

// ---------------------------------------------------------------- per-bucket fine CSR (pure: off + esrc only)
__global__ __launch_bounds__(256) void k_bucket_csr(
    const int* __restrict__ bcur, const unsigned int* __restrict__ epack,
    int* __restrict__ off_s, int* __restrict__ off_e, int* __restrict__ esrc) {
    __shared__ int lh[128];
    __shared__ int lcur[128];
    __shared__ int sblk;
    const int tid = threadIdx.x, lane = tid & 63;
    const int b = blockIdx.x;
    const int e0 = b * BCAP;
    const int cnt = bcur[b] - e0;

    if (tid < 128) lh[tid] = 0;
    __syncthreads();
    for (int i = tid; i < cnt; i += 256)
        atomicAdd(&lh[epack[e0 + i] >> 16], 1);
    __syncthreads();

    int v = 0, incl = 0;
    if (tid < 128) {
        v = lh[tid];
        incl = v;
#pragma unroll
        for (int s = 1; s < 64; s <<= 1) {
            int t = __shfl_up(incl, s);
            if (lane >= s) incl += t;
        }
    }
    if (tid == 63) sblk = incl;
    __syncthreads();
    if (tid >= 64 && tid < 128) incl += sblk;
    if (tid < 128) {
        int ex = e0 + incl - v;
        lcur[tid] = ex;
        int gd = b * 128 + tid;
        if (gd < NN) { off_s[gd] = ex; off_e[gd] = ex + v; }
    }
    __syncthreads();

    for (int i = tid; i < cnt; i += 256) {
        unsigned int p = epack[e0 + i];
        int pos = atomicAdd(&lcur[p >> 16], 1);
        esrc[pos] = (int)(p & 0xFFFFu);
    }
}

// ---------------------------------------------------------------- GEMM1: x(50000x128)@W1(128x64), 4x4 reg tile, fp16 h1 out
// also inits bcur (runs first in stream order)
__global__ __launch_bounds__(256, 2) void k_gemm1(
    const float* __restrict__ x, const float* __restrict__ W1,
    const float* __restrict__ a_s, const float* __restrict__ a_d,
    __half* __restrict__ h1h, float* __restrict__ asrc1, float* __restrict__ adst1,
    int* __restrict__ bcur)
{
    __shared__ float Wl[INDIM * HID];      // 32 KB
    __shared__ float xs[64 * 132];         // 33.8 KB, padded stride 132
    const int tid = threadIdx.x;
    const int r0 = blockIdx.x * 64;

    if (blockIdx.x == 0) {
        for (int i = tid; i < NB; i += 256) bcur[i] = i * BCAP;
    }

    const float4* W4 = (const float4*)W1;
    float4* Wl4 = (float4*)Wl;
#pragma unroll
    for (int i = 0; i < 8; ++i) Wl4[tid + i * 256] = W4[tid + i * 256];

    const float4* x4 = (const float4*)x;
#pragma unroll
    for (int i = 0; i < 8; ++i) {
        int idx = tid + i * 256;           // 0..2047
        int row = idx >> 5;                // 32 float4 per row
        int k4  = idx & 31;
        int nr = r0 + row;
        float4 v = make_float4(0.f, 0.f, 0.f, 0.f);
        if (nr < NN) v = x4[(size_t)nr * 32 + k4];
        *(float4*)&xs[row * 132 + k4 * 4] = v;
    }
    __syncthreads();

    const int rg = tid >> 4;               // 0..15 (4 rows each)
    const int cg = tid & 15;
    const int c4 = cg * 4;
    const float as0 = a_s[c4], as1v = a_s[c4+1], as2v = a_s[c4+2], as3v = a_s[c4+3];
    const float ad0 = a_d[c4], ad1v = a_d[c4+1], ad2v = a_d[c4+2], ad3v = a_d[c4+3];

    float acc[4][4];
#pragma unroll
    for (int i = 0; i < 4; ++i)
#pragma unroll
        for (int j = 0; j < 4; ++j) acc[i][j] = 0.f;

#pragma unroll 4
    for (int k4 = 0; k4 < 32; ++k4) {
        float4 xv[4];
#pragma unroll
        for (int i = 0; i < 4; ++i)
            xv[i] = *(const float4*)&xs[(rg * 4 + i) * 132 + k4 * 4];
        const float* wp = &Wl[(k4 * 4) * HID + c4];
        float4 w0 = *(const float4*)(wp);
        float4 w1 = *(const float4*)(wp + HID);
        float4 w2 = *(const float4*)(wp + 2 * HID);
        float4 w3 = *(const float4*)(wp + 3 * HID);
#pragma unroll
        for (int i = 0; i < 4; ++i) {
            acc[i][0] += xv[i].x * w0.x + xv[i].y * w1.x + xv[i].z * w2.x + xv[i].w * w3.x;
            acc[i][1] += xv[i].x * w0.y + xv[i].y * w1.y + xv[i].z * w2.y + xv[i].w * w3.y;
            acc[i][2] += xv[i].x * w0.z + xv[i].y * w1.z + xv[i].z * w2.z + xv[i].w * w3.z;
            acc[i][3] += xv[i].x * w0.w + xv[i].y * w1.w + xv[i].z * w2.w + xv[i].w * w3.w;
        }
    }

#pragma unroll
    for (int i = 0; i < 4; ++i) {
        const int n = r0 + rg * 4 + i;
        if (n < NN) {
            __half2 ha = __floats2half2_rn(acc[i][0], acc[i][1]);
            __half2 hb = __floats2half2_rn(acc[i][2], acc[i][3]);
            *(__half2*)&h1h[(size_t)n * HID + c4]     = ha;
            *(__half2*)&h1h[(size_t)n * HID + c4 + 2] = hb;
        }
        float ps = acc[i][0] * as0 + acc[i][1] * as1v + acc[i][2] * as2v + acc[i][3] * as3v;
        float pd = acc[i][0] * ad0 + acc[i][1] * ad1v + acc[i][2] * ad2v + acc[i][3] * ad3v;
        ps += __shfl_xor(ps, 1); ps += __shfl_xor(ps, 2);
        pd += __shfl_xor(pd, 1); pd += __shfl_xor(pd, 2);
        if ((cg & 3) == 0 && n < NN) {
            int head = cg >> 2;
            asrc1[n * 4 + head] = ps;
            adst1[n * 4 + head] = pd;
        }
    }
}

// ---------------------------------------------------------------- layer-1 aggregate: 4 nodes/wave, 16 lanes x 4 dims, inline exp
__global__ __launch_bounds__(256) void k_fagg1(
    const int* __restrict__ off_s, const int* __restrict__ off_e,
    const int* __restrict__ esrc, const float* __restrict__ asrc1,
    const float* __restrict__ adst1,
    const __half* __restrict__ h1h, const float* __restrict__ b1,
    __half* __restrict__ hmid)
{
    const int wv = threadIdx.x >> 6, lane = threadIdx.x & 63;
    const int g = lane >> 4, li = lane & 15;      // 4 nodes/wave, 16 lanes each
    const int n = blockIdx.x * 16 + wv * 4 + g;   // grid exact: 3125*16 = 50000
    const int s0 = off_s[n], s1 = off_e[n];
    const int hp = li >> 2;                       // head
    const float adst = adst1[n * 4 + hp];
    const int last = s1 - 1;

    float l = 0.f, a0 = 0.f, a1 = 0.f, a2 = 0.f, a3 = 0.f;
    const char* hb = (const char*)h1h;
    for (int t = s0; t < s1; t += 8) {
        int sx[8];
        int ok[8];
#pragma unroll
        for (int j = 0; j < 8; ++j) {
            int ix  = t + j;
            ok[j] = (ix < s1);
            int ixc = ok[j] ? ix : last;
            sx[j] = esrc[ixc];
        }
        float ax[8];
#pragma unroll
        for (int j = 0; j < 8; ++j) ax[j] = asrc1[sx[j] * 4 + hp];
        float2 f0[8], f1[8];
#pragma unroll
        for (int j = 0; j < 8; ++j) {
            uint2 raw = *(const uint2*)(hb + ((size_t)sx[j] * 128 + li * 8));
            f0[j] = __half22float2(*(__half2*)&raw.x);
            f1[j] = __half22float2(*(__half2*)&raw.y);
        }
#pragma unroll
        for (int j = 0; j < 8; ++j) {
            float e = ax[j] + adst;
            e = (e > 0.f) ? e : 0.2f * e;
            float w = __expf(e);
            w = ok[j] ? w : 0.f;
            l  += w;
            a0 += w * f0[j].x;
            a1 += w * f0[j].y;
            a2 += w * f1[j].x;
            a3 += w * f1[j].y;
        }
    }
    float rcp = 1.f / l;
    float4 bv = *(const float4*)&b1[li * 4];
    float o0 = fmaxf(a0 * rcp + bv.x, 0.f);
    float o1 = fmaxf(a1 * rcp + bv.y, 0.f);
    float o2 = fmaxf(a2 * rcp + bv.z, 0.f);
    float o3 = fmaxf(a3 * rcp + bv.w, 0.f);
    __half2 ha = __floats2half2_rn(o0, o1);
    __half2 hc = __floats2half2_rn(o2, o3);
    uint2 st;
    st.x = *(unsigned*)&ha;
    st.y = *(unsigned*)&hc;
    *(uint2*)((char*)hmid + ((size_t)n * 128 + li * 8)) = st;
}

// ---------------------------------------------------------------- GEMM2: hmid_fp16(50000x64) @ W2(64x40), fp16 h2 out
__global__ __launch_bounds__(320) void k_gemm2(
    const __half* __restrict__ hin, const float* __restrict__ W2,
    const float* __restrict__ a_s, const float* __restrict__ a_d,
    __half* __restrict__ h2h, float* __restrict__ asrc2, float* __restrict__ adst2)
{
    __shared__ float Wl[HID * OUTD];       // 2560 floats
    __shared__ float xs[32 * 68];          // padded stride 68
    __shared__ float s_as[32], s_ad[32];
    const int tid = threadIdx.x;
    const int r0 = blockIdx.x * 32;

    const float4* W4 = (const float4*)W2;  // 640 float4
    float4* Wl4 = (float4*)Wl;
    for (int i = tid; i < 640; i += 320) Wl4[i] = W4[i];
    const uint2* x4 = (const uint2*)hin;   // 4 halfs per uint2; 16 per row
    for (int i = tid; i < 512; i += 320) {
        int row = i >> 4;
        int c   = i & 15;
        int nr = r0 + row;
        float4 v = make_float4(0.f, 0.f, 0.f, 0.f);
        if (nr < NN) {
            uint2 raw = x4[(size_t)nr * 16 + c];
            float2 p0 = __half22float2(*(__half2*)&raw.x);
            float2 p1 = __half22float2(*(__half2*)&raw.y);
            v = make_float4(p0.x, p0.y, p1.x, p1.y);
        }
        *(float4*)&xs[row * 68 + c * 4] = v;
    }
    if (tid < 32) { s_as[tid] = 0.f; s_ad[tid] = 0.f; }
    __syncthreads();

    const int r  = tid / 10;               // 0..31
    const int cg = tid % 10;
    const int c4 = cg * 4;                 // 0..36
    float a0 = 0.f, a1 = 0.f, a2 = 0.f, a3 = 0.f;
#pragma unroll 4
    for (int k4 = 0; k4 < 16; ++k4) {
        float4 xv = *(const float4*)&xs[r * 68 + k4 * 4];
        const float* wp = &Wl[(k4 * 4) * OUTD + c4];
        float4 w0 = *(const float4*)(wp);
        float4 w1 = *(const float4*)(wp + OUTD);
        float4 w2 = *(const float4*)(wp + 2 * OUTD);
        float4 w3 = *(const float4*)(wp + 3 * OUTD);
        a0 += xv.x * w0.x + xv.y * w1.x + xv.z * w2.x + xv.w * w3.x;
        a1 += xv.x * w0.y + xv.y * w1.y + xv.z * w2.y + xv.w * w3.y;
        a2 += xv.x * w0.z + xv.y * w1.z + xv.z * w2.z + xv.w * w3.z;
        a3 += xv.x * w0.w + xv.y * w1.w + xv.z * w2.w + xv.w * w3.w;
    }
    const int n = r0 + r;
    float ps = a0 * a_s[c4] + a1 * a_s[c4 + 1] + a2 * a_s[c4 + 2] + a3 * a_s[c4 + 3];
    float pd = a0 * a_d[c4] + a1 * a_d[c4 + 1] + a2 * a_d[c4 + 2] + a3 * a_d[c4 + 3];
    atomicAdd(&s_as[r], ps);
    atomicAdd(&s_ad[r], pd);
    if (n < NN) {
        __half2 ha = __floats2half2_rn(a0, a1);
        __half2 hb = __floats2half2_rn(a2, a3);
        *(__half2*)&h2h[(size_t)n * OUTD + c4]     = ha;
        *(__half2*)&h2h[(size_t)n * OUTD + c4 + 2] = hb;
    }
    __syncthreads();
    if (tid < 32) {
        int n2 = r0 + tid;
        if (n2 < NN) { asrc2[n2] = s_as[tid]; adst2[n2] = s_ad[tid]; }
    }
}

// ---------------------------------------------------------------- layer-2 aggregate: 6 nodes/wave, inline exp, LDS log_softmax
__global__ __launch_bounds__(256) void k_fagg2(
    const int* __restrict__ off_s, const int* __restrict__ off_e,
    const int* __restrict__ esrc, const float* __restrict__ asrc2,
    const float* __restrict__ adst2,
    const __half* __restrict__ h2h, const float* __restrict__ b2,
    float* __restrict__ out)
{
    __shared__ float svals[24][OUTD];
    const int wv = threadIdx.x >> 6, lane = threadIdx.x & 63;
    const int g = lane / 10;                       // 0..6 (g==6 idle)
    const int li = lane - g * 10;                  // 0..9
    const bool ga = (g < 6);
    const int n = blockIdx.x * 24 + wv * 6 + (ga ? g : 0);
    const bool valid = ga && (n < NN);
    const int s0 = valid ? off_s[n] : 0;
    const int s1 = valid ? off_e[n] : 0;
    const float adst = valid ? adst2[n] : 0.f;
    const int last = s1 - 1;

    float l = 0.f, a0 = 0.f, a1 = 0.f, a2 = 0.f, a3 = 0.f;
    const char* hb = (const char*)h2h;
    for (int t = s0; t < s1; t += 8) {
        int sx[8];
        int ok[8];
#pragma unroll
        for (int j = 0; j < 8; ++j) {
            int ix  = t + j;
            ok[j] = (ix < s1);
            int ixc = ok[j] ? ix : last;
            sx[j] = esrc[ixc];
        }
        float ax[8];
#pragma unroll
        for (int j = 0; j < 8; ++j) ax[j] = asrc2[sx[j]];
        float2 f0[8], f1[8];
#pragma unroll
        for (int j = 0; j < 8; ++j) {
            uint2 raw = *(const uint2*)(hb + ((size_t)sx[j] * 80 + li * 8));
            f0[j] = __half22float2(*(__half2*)&raw.x);
            f1[j] = __half22float2(*(__half2*)&raw.y);
        }
#pragma unroll
        for (int j = 0; j < 8; ++j) {
            float e = ax[j] + adst;
            e = (e > 0.f) ? e : 0.2f * e;
            float w = __expf(e);
            w = ok[j] ? w : 0.f;
            l  += w;
            a0 += w * f0[j].x;
            a1 += w * f0[j].y;
            a2 += w * f1[j].x;
            a3 += w * f1[j].y;
        }
    }
    if (valid) {
        float rcp = 1.f / l;
        float4 bv = *(const float4*)&b2[li * 4];
        int r = wv * 6 + g;
        svals[r][li * 4]     = a0 * rcp + bv.x;
        svals[r][li * 4 + 1] = a1 * rcp + bv.y;
        svals[r][li * 4 + 2] = a2 * rcp + bv.z;
        svals[r][li * 4 + 3] = a3 * rcp + bv.w;
    }
    __syncthreads();

    for (int r = wv; r < 24; r += 4) {
        int n2 = blockIdx.x * 24 + r;
        if (n2 >= NN) continue;
        float v = (lane < OUTD) ? svals[r][lane] : -1e30f;
        float mx = v;
#pragma unroll
        for (int o = 32; o; o >>= 1) mx = fmaxf(mx, __shfl_xor(mx, o));
        float ex = (lane < OUTD) ? __expf(v - mx) : 0.f;
        float sm = ex;
#pragma unroll
        for (int o = 32; o; o >>= 1) sm += __shfl_xor(sm, o);
        if (lane < OUTD) out[(size_t)n2 * OUTD + lane] = v - mx - __logf(sm);
    }
}

// ----------------------------------------------------------------
extern "C" void kernel_launch(void* const* d_in, const int* in_sizes, int n_in,
                              void* d_out, int out_size, void* d_ws, size_t ws_size,
                              hipStream_t stream)
{
    const float* x   = (const float*)d_in[0];
    const int*   ei  = (const int*)  d_in[1];
    const float* W1  = (const float*)d_in[2];
    const float* as1 = (const float*)d_in[3];
    const float* ad1 = (const float*)d_in[4];
    const float* b1  = (const float*)d_in[5];
    const float* W2  = (const float*)d_in[6];
    const float* as2 = (const float*)d_in[7];
    const float* ad2 = (const float*)d_in[8];
    const float* b2  = (const float*)d_in[9];
    float* out = (float*)d_out;

    // flat workspace layout (~30 MB of the 268 MB available)
    char* ws = (char*)d_ws;
    __half* h1h   = (__half*)(ws);                        //  6,400,000 B
    __half* hmidh = (__half*)(ws +  6400000);             //  6,400,000 B
    __half* h2h   = (__half*)(ws + 12800000);             //  4,000,000 B
    float*  asrc1 = (float*) (ws + 16800000);             //    800,000 B
    float*  adst1 = (float*) (ws + 17600000);             //    800,000 B
    float*  asrc2 = (float*) (ws + 18400000);             //    200,000 B
    float*  adst2 = (float*) (ws + 18600000);             //    200,000 B
    int*    off_s = (int*)   (ws + 18800000);             //    200,000 B
    int*    off_e = (int*)   (ws + 19000000);             //    200,000 B
    unsigned int* epack = (unsigned int*)(ws + 19200000); //  4,804,608 B (NB*BCAP*4)
    int*    esrc  = (int*)   (ws + 24004608);             //  4,804,608 B
    int*    bcur  = (int*)   (ws + 28809216);             //      1,564 B

    hipLaunchKernelGGL(k_gemm1,      dim3(782),  dim3(256), 0, stream, x, W1, as1, ad1, h1h, asrc1, adst1, bcur);
    hipLaunchKernelGGL(k_bin,        dim3(256),  dim3(256), 0, stream, ei, bcur, epack);
    hipLaunchKernelGGL(k_bucket_csr, dim3(NB),   dim3(256), 0, stream, bcur, epack, off_s, off_e, esrc);
    hipLaunchKernelGGL(k_fagg1,      dim3(3125), dim3(256), 0, stream, off_s, off_e, esrc, asrc1, adst1, h1h, b1, hmidh);
    hipLaunchKernelGGL(k_gemm2,      dim3(1563), dim3(320), 0, stream, hmidh, W2, as2, ad2, h2h, asrc2, adst2);
    hipLaunchKernelGGL(k_fagg2,      dim3(2084), dim3(256), 0, stream, off_s, off_e, esrc, asrc2, adst2, h2h, b2, out);
}